// Round 4
// baseline (333.524 us; speedup 1.0000x reference)
//
#include <hip/hip_runtime.h>
#include <hip/hip_bf16.h>

// Shapes: n_atoms=50000, hidden=32, num_irreps=16, out_ch=32, n_edges=800000
// Strategy:
//   P[a] = nf[a] @ W  (bf16, layout [a][c][i], 1 KB/atom)  -- W folded early
//   CSR by target (histogram + scan + scatter of 16 B edge records)
//   one wave per target atom: gather P[src] rows, Y-contraction, register
//   accumulation, shuffle-reduce, single coalesced store. No output atomics.

#define HIDDEN 32
#define IRREPS 16
#define OUTCH  32
#define PPAIRS 256          // bf162 pairs per atom (512 bf16)
#define APB    32           // atoms per block in compute_P

// ---------------- Kernel 1: P (bf16, [a][c][i] layout), W in registers -----
__global__ __launch_bounds__(256)
void compute_P_kernel(const float* __restrict__ nf,
                      const float* __restrict__ W,
                      __hip_bfloat162* __restrict__ P2, int n_atoms) {
    __shared__ float s_nf[APB * HIDDEN];     // 4 KB
    const int t  = threadIdx.x;
    const int c  = t >> 3;                   // 0..31 output channel
    const int ip = t & 7;                    // 0..7  i-pair
    const int j0 = (2 * ip) * OUTCH + c;
    const int j1 = j0 + OUTCH;

    float w0[HIDDEN], w1[HIDDEN];
#pragma unroll
    for (int h = 0; h < HIDDEN; ++h) {
        w0[h] = W[h * 512 + j0];
        w1[h] = W[h * 512 + j1];
    }

    const int a0 = blockIdx.x * APB;
    // stage nf rows for this block's atoms (coalesced float4)
    {
        const int base = a0 * HIDDEN + t * 4;       // float index
        if (base + 3 < n_atoms * HIDDEN) {
            ((float4*)s_nf)[t] = *(const float4*)(nf + base);
        }
    }
    __syncthreads();

    const int amax = min(APB, n_atoms - a0);
    for (int al = 0; al < amax; ++al) {
        float acc0 = 0.f, acc1 = 0.f;
#pragma unroll
        for (int h = 0; h < HIDDEN; ++h) {
            const float n = s_nf[al * HIDDEN + h];   // LDS broadcast
            acc0 = fmaf(n, w0[h], acc0);
            acc1 = fmaf(n, w1[h], acc1);
        }
        __hip_bfloat162 pk;
        pk.x = __float2bfloat16(acc0);
        pk.y = __float2bfloat16(acc1);
        P2[(a0 + al) * PPAIRS + t] = pk;    // pair index == c*8+ip == t
    }
}

// ---------------- CSR build -------------------------------------------------
__global__ void zero_counts_kernel(int* __restrict__ counts, int n) {
    int i = blockIdx.x * blockDim.x + threadIdx.x;
    if (i < n) counts[i] = 0;
}

__global__ void histogram_kernel(const int* __restrict__ ei,
                                 int* __restrict__ counts, int n_edges) {
    int e = blockIdx.x * blockDim.x + threadIdx.x;
    if (e < n_edges) atomicAdd(&counts[ei[n_edges + e]], 1);
}

__global__ __launch_bounds__(256)
void scan_blocks_kernel(const int* __restrict__ counts,
                        int* __restrict__ partial,
                        int* __restrict__ blocksums, int n) {
    __shared__ int s[256];
    const int tid = threadIdx.x;
    const int i = blockIdx.x * 256 + tid;
    const int v = (i < n) ? counts[i] : 0;
    s[tid] = v;
    __syncthreads();
    for (int off = 1; off < 256; off <<= 1) {
        int add = 0;
        if (tid >= off) add = s[tid - off];
        __syncthreads();
        if (tid >= off) s[tid] += add;
        __syncthreads();
    }
    if (i < n) partial[i] = s[tid] - v;          // exclusive within block
    if (tid == 255) blocksums[blockIdx.x] = s[255];
}

__global__ void scan_sums_kernel(int* __restrict__ blocksums, int nb) {
    if (blockIdx.x == 0 && threadIdx.x == 0) {
        int run = 0;
        for (int j = 0; j < nb; ++j) { int t = blocksums[j]; blocksums[j] = run; run += t; }
    }
}

__global__ void add_offsets_kernel(const int* __restrict__ partial,
                                   const int* __restrict__ blocksums,
                                   int* __restrict__ offsets,
                                   int* __restrict__ cursor, int n) {
    int i = blockIdx.x * blockDim.x + threadIdx.x;
    if (i < n) {
        int off = partial[i] + blocksums[i >> 8];
        offsets[i] = off;
        cursor[i]  = off;
    }
}

__global__ void scatter_records_kernel(const float* __restrict__ ev,
                                       const int* __restrict__ ei,
                                       int* __restrict__ cursor,
                                       float4* __restrict__ recs, int n_edges) {
    int e = blockIdx.x * blockDim.x + threadIdx.x;
    if (e >= n_edges) return;
    const int src = ei[e];
    const int tgt = ei[n_edges + e];
    const float vx = ev[3 * e + 0];
    const float vy = ev[3 * e + 1];
    const float vz = ev[3 * e + 2];
    const float r    = sqrtf(vx * vx + vy * vy + vz * vz);
    const float rinv = 1.0f / fmaxf(r, 1e-12f);
    const int pos = atomicAdd(&cursor[tgt], 1);
    recs[pos] = make_float4(__int_as_float(src), vx * rinv, vy * rinv, vz * rinv);
}

// ---------------- accumulate: one wave per target atom ---------------------
__device__ __forceinline__ float2 bf2f2(unsigned u) {
    return __bfloat1622float2(*(const __hip_bfloat162*)&u);
}

__global__ __launch_bounds__(256)
void accumulate_kernel(const float4* __restrict__ recs,
                       const int* __restrict__ offsets,
                       const int* __restrict__ counts,
                       const __hip_bfloat162* __restrict__ P2,
                       const float* __restrict__ b,
                       float* __restrict__ out, int n_atoms) {
    const int gtid = blockIdx.x * blockDim.x + threadIdx.x;
    const int t = gtid >> 6;                 // one wave per atom
    if (t >= n_atoms) return;
    const int lane = threadIdx.x & 63;
    const int slot = lane >> 4;              // 0..3: edge slot
    const int sub  = lane & 15;              // channel pair: c0=2sub, c1=2sub+1

    const int start = offsets[t];
    const int k     = counts[t];

    float m0 = 0.f, m1 = 0.f;
    for (int j = slot; j < k; j += 4) {
        const float4 rec = recs[start + j];
        const int src = __float_as_int(rec.x);
        const float x = rec.y, y = rec.z, z = rec.w;
        const float x2 = x * x, y2 = y * y, z2 = z * z;

        float Y[IRREPS];
        Y[0]  = 0.28209479177387814f;
        Y[1]  = 0.4886025119029199f * y;
        Y[2]  = 0.4886025119029199f * z;
        Y[3]  = 0.4886025119029199f * x;
        Y[4]  = 1.0925484305920792f * x * y;
        Y[5]  = 1.0925484305920792f * y * z;
        Y[6]  = 0.31539156525252005f * (3.0f * z2 - 1.0f);
        Y[7]  = 1.0925484305920792f * x * z;
        Y[8]  = 0.5462742152960396f * (x2 - y2);
        Y[9]  = 0.5900435899266435f * y * (3.0f * x2 - y2);
        Y[10] = 2.890611442640554f * x * y * z;
        Y[11] = 0.4570457994644658f * y * (5.0f * z2 - 1.0f);
        Y[12] = 0.3731763325901154f * z * (5.0f * z2 - 3.0f);
        Y[13] = 0.4570457994644658f * x * (5.0f * z2 - 1.0f);
        Y[14] = 1.445305721320277f * z * (x2 - y2);
        Y[15] = 0.5900435899266435f * x * (x2 - 3.0f * y2);

        // contiguous 64 B: pairs [16*sub .. 16*sub+15] of atom src
        const uint4* q = (const uint4*)(P2 + src * PPAIRS + 16 * sub);
        const uint4 A = q[0];   // c0, i 0..7
        const uint4 B = q[1];   // c0, i 8..15
        const uint4 C = q[2];   // c1, i 0..7
        const uint4 D = q[3];   // c1, i 8..15

        float2 p;
        p = bf2f2(A.x); m0 = fmaf(Y[0],  p.x, m0); m0 = fmaf(Y[1],  p.y, m0);
        p = bf2f2(A.y); m0 = fmaf(Y[2],  p.x, m0); m0 = fmaf(Y[3],  p.y, m0);
        p = bf2f2(A.z); m0 = fmaf(Y[4],  p.x, m0); m0 = fmaf(Y[5],  p.y, m0);
        p = bf2f2(A.w); m0 = fmaf(Y[6],  p.x, m0); m0 = fmaf(Y[7],  p.y, m0);
        p = bf2f2(B.x); m0 = fmaf(Y[8],  p.x, m0); m0 = fmaf(Y[9],  p.y, m0);
        p = bf2f2(B.y); m0 = fmaf(Y[10], p.x, m0); m0 = fmaf(Y[11], p.y, m0);
        p = bf2f2(B.z); m0 = fmaf(Y[12], p.x, m0); m0 = fmaf(Y[13], p.y, m0);
        p = bf2f2(B.w); m0 = fmaf(Y[14], p.x, m0); m0 = fmaf(Y[15], p.y, m0);
        p = bf2f2(C.x); m1 = fmaf(Y[0],  p.x, m1); m1 = fmaf(Y[1],  p.y, m1);
        p = bf2f2(C.y); m1 = fmaf(Y[2],  p.x, m1); m1 = fmaf(Y[3],  p.y, m1);
        p = bf2f2(C.z); m1 = fmaf(Y[4],  p.x, m1); m1 = fmaf(Y[5],  p.y, m1);
        p = bf2f2(C.w); m1 = fmaf(Y[6],  p.x, m1); m1 = fmaf(Y[7],  p.y, m1);
        p = bf2f2(D.x); m1 = fmaf(Y[8],  p.x, m1); m1 = fmaf(Y[9],  p.y, m1);
        p = bf2f2(D.y); m1 = fmaf(Y[10], p.x, m1); m1 = fmaf(Y[11], p.y, m1);
        p = bf2f2(D.z); m1 = fmaf(Y[12], p.x, m1); m1 = fmaf(Y[13], p.y, m1);
        p = bf2f2(D.w); m1 = fmaf(Y[14], p.x, m1); m1 = fmaf(Y[15], p.y, m1);
    }

    // reduce the 4 edge slots (lanes differing in bits 4,5)
    m0 += __shfl_xor(m0, 16); m0 += __shfl_xor(m0, 32);
    m1 += __shfl_xor(m1, 16); m1 += __shfl_xor(m1, 32);

    if (slot == 0) {
        const float2 bb = ((const float2*)b)[sub];
        ((float2*)out)[t * (OUTCH / 2) + sub] = make_float2(m0 + bb.x, m1 + bb.y);
    }
}

// ---------------- launch ---------------------------------------------------
extern "C" void kernel_launch(void* const* d_in, const int* in_sizes, int n_in,
                              void* d_out, int out_size, void* d_ws, size_t ws_size,
                              hipStream_t stream) {
    const float* nf = (const float*)d_in[0];
    const float* ev = (const float*)d_in[1];
    const int*   ei = (const int*)d_in[2];
    const float* W  = (const float*)d_in[3];
    const float* b  = (const float*)d_in[4];
    float* out = (float*)d_out;

    const int n_atoms = in_sizes[0] / HIDDEN;
    const int n_edges = in_sizes[1] / 3;
    const int nblk    = (n_atoms + 255) / 256;   // scan blocks

    // workspace carve-up (256 B aligned)
    char* ws = (char*)d_ws;
    size_t off = 0;
    auto carve = [&](size_t bytes) { void* p = ws + off; off = (off + bytes + 255) & ~(size_t)255; return p; };
    __hip_bfloat162* P2    = (__hip_bfloat162*)carve((size_t)n_atoms * PPAIRS * 4);
    float4*          recs  = (float4*)carve((size_t)n_edges * 16);
    int* counts    = (int*)carve((size_t)n_atoms * 4);
    int* offsets   = (int*)carve((size_t)n_atoms * 4);
    int* cursor    = (int*)carve((size_t)n_atoms * 4);
    int* partial   = (int*)carve((size_t)n_atoms * 4);
    int* blocksums = (int*)carve((size_t)nblk * 4);

    compute_P_kernel<<<(n_atoms + APB - 1) / APB, 256, 0, stream>>>(nf, W, P2, n_atoms);

    zero_counts_kernel<<<nblk, 256, 0, stream>>>(counts, n_atoms);
    histogram_kernel<<<(n_edges + 255) / 256, 256, 0, stream>>>(ei, counts, n_edges);
    scan_blocks_kernel<<<nblk, 256, 0, stream>>>(counts, partial, blocksums, n_atoms);
    scan_sums_kernel<<<1, 64, 0, stream>>>(blocksums, nblk);
    add_offsets_kernel<<<nblk, 256, 0, stream>>>(partial, blocksums, offsets, cursor, n_atoms);
    scatter_records_kernel<<<(n_edges + 255) / 256, 256, 0, stream>>>(ev, ei, cursor, recs, n_edges);

    const long long waves = (long long)n_atoms * 64;
    accumulate_kernel<<<(int)((waves + 255) / 256), 256, 0, stream>>>(
        recs, offsets, counts, P2, b, out, n_atoms);
}

// Round 5
// 261.707 us; speedup vs baseline: 1.2744x; 1.2744x over previous
//
#include <hip/hip_runtime.h>
#include <hip/hip_bf16.h>

// Shapes: n_atoms=50000, hidden=32, num_irreps=16, out_ch=32, n_edges=800000
// Pipeline:
//   CSR by target (histogram + scan + scatter of 16 B records (src, x,y,z))
//   accumulate: one wave per target atom, gathers nf[src] (6.4 MB, L2-resident)
//               and accumulates agg[t][h*16+i] = sum_e nf[src,h]*Y_e[i] in regs,
//               stores agg as bf16 (row-major, 1 KB/atom).
//   GEMM: out = agg @ W + b via mfma_f32_16x16x32_bf16. agg rows are natively
//         A-fragment-ordered (A[m=lane&15][k=quad*8+j]); W is pre-swizzled to
//         B-fragment order (32 KB, cache-resident).

#define HIDDEN 32
#define IRREPS 16
#define OUTCH  32

// ---------------- CSR build -------------------------------------------------
__global__ void histogram_kernel(const int* __restrict__ ei,
                                 int* __restrict__ counts, int n_edges) {
    int e = blockIdx.x * blockDim.x + threadIdx.x;
    if (e < n_edges) atomicAdd(&counts[ei[n_edges + e]], 1);
}

__global__ __launch_bounds__(256)
void scan_blocks_kernel(const int* __restrict__ counts,
                        int* __restrict__ partial,
                        int* __restrict__ blocksums, int n) {
    __shared__ int s[256];
    const int tid = threadIdx.x;
    const int i = blockIdx.x * 256 + tid;
    const int v = (i < n) ? counts[i] : 0;
    s[tid] = v;
    __syncthreads();
    for (int off = 1; off < 256; off <<= 1) {
        int add = 0;
        if (tid >= off) add = s[tid - off];
        __syncthreads();
        if (tid >= off) s[tid] += add;
        __syncthreads();
    }
    if (i < n) partial[i] = s[tid] - v;          // exclusive within block
    if (tid == 255) blocksums[blockIdx.x] = s[255];
}

// nb <= 256: single-block parallel exclusive scan
__global__ __launch_bounds__(256)
void scan_sums_kernel(int* __restrict__ blocksums, int nb) {
    __shared__ int s[256];
    const int tid = threadIdx.x;
    const int v = (tid < nb) ? blocksums[tid] : 0;
    s[tid] = v;
    __syncthreads();
    for (int off = 1; off < 256; off <<= 1) {
        int add = 0;
        if (tid >= off) add = s[tid - off];
        __syncthreads();
        if (tid >= off) s[tid] += add;
        __syncthreads();
    }
    if (tid < nb) blocksums[tid] = s[tid] - v;   // exclusive
}

__global__ void add_offsets_kernel(const int* __restrict__ partial,
                                   const int* __restrict__ blocksums,
                                   int* __restrict__ offsets,
                                   int* __restrict__ cursor, int n) {
    int i = blockIdx.x * blockDim.x + threadIdx.x;
    if (i < n) {
        int off = partial[i] + blocksums[i >> 8];
        offsets[i] = off;
        cursor[i]  = off;
    }
}

__global__ void scatter_records_kernel(const float* __restrict__ ev,
                                       const int* __restrict__ ei,
                                       int* __restrict__ cursor,
                                       float4* __restrict__ recs, int n_edges) {
    int e = blockIdx.x * blockDim.x + threadIdx.x;
    if (e >= n_edges) return;
    const int src = ei[e];
    const int tgt = ei[n_edges + e];
    const float vx = ev[3 * e + 0];
    const float vy = ev[3 * e + 1];
    const float vz = ev[3 * e + 2];
    const float r    = sqrtf(vx * vx + vy * vy + vz * vz);
    const float rinv = 1.0f / fmaxf(r, 1e-12f);
    const int pos = atomicAdd(&cursor[tgt], 1);
    recs[pos] = make_float4(__int_as_float(src), vx * rinv, vy * rinv, vz * rinv);
}

// ---------------- accumulate: one wave per target atom ---------------------
// lane owns (h = lane>>1, i-half = lane&1): cells agg[h][ih*8 .. ih*8+7]
__global__ __launch_bounds__(256)
void accumulate_agg_kernel(const float4* __restrict__ recs,
                           const int* __restrict__ offsets,
                           const int* __restrict__ counts,
                           const float* __restrict__ nf,
                           __hip_bfloat16* __restrict__ aggb, int n_atoms) {
    const int w = (blockIdx.x * blockDim.x + threadIdx.x) >> 6;
    if (w >= n_atoms) return;
    const int lane = threadIdx.x & 63;
    const int h  = lane >> 1;
    const int ih = lane & 1;

    const int start = offsets[w];
    const int k     = counts[w];

    float a0 = 0.f, a1 = 0.f, a2 = 0.f, a3 = 0.f;
    float a4 = 0.f, a5 = 0.f, a6 = 0.f, a7 = 0.f;

    for (int j = 0; j < k; ++j) {
        const float4 rec = recs[start + j];          // wave-uniform 16 B
        const int src = __float_as_int(rec.x);
        const float x = rec.y, y = rec.z, z = rec.w;
        const float v = nf[src * HIDDEN + h];        // coalesced 128 B/wave

        const float x2 = x * x, y2 = y * y, z2 = z * z;
        const float Y0  = 0.28209479177387814f;
        const float Y1  = 0.4886025119029199f * y;
        const float Y2  = 0.4886025119029199f * z;
        const float Y3  = 0.4886025119029199f * x;
        const float Y4  = 1.0925484305920792f * x * y;
        const float Y5  = 1.0925484305920792f * y * z;
        const float Y6  = 0.31539156525252005f * (3.0f * z2 - 1.0f);
        const float Y7  = 1.0925484305920792f * x * z;
        const float Y8  = 0.5462742152960396f * (x2 - y2);
        const float Y9  = 0.5900435899266435f * y * (3.0f * x2 - y2);
        const float Y10 = 2.890611442640554f * x * y * z;
        const float Y11 = 0.4570457994644658f * y * (5.0f * z2 - 1.0f);
        const float Y12 = 0.3731763325901154f * z * (5.0f * z2 - 3.0f);
        const float Y13 = 0.4570457994644658f * x * (5.0f * z2 - 1.0f);
        const float Y14 = 1.445305721320277f * z * (x2 - y2);
        const float Y15 = 0.5900435899266435f * x * (x2 - 3.0f * y2);

        const float s0 = ih ? Y8  : Y0;
        const float s1 = ih ? Y9  : Y1;
        const float s2 = ih ? Y10 : Y2;
        const float s3 = ih ? Y11 : Y3;
        const float s4 = ih ? Y12 : Y4;
        const float s5 = ih ? Y13 : Y5;
        const float s6 = ih ? Y14 : Y6;
        const float s7 = ih ? Y15 : Y7;

        a0 = fmaf(v, s0, a0); a1 = fmaf(v, s1, a1);
        a2 = fmaf(v, s2, a2); a3 = fmaf(v, s3, a3);
        a4 = fmaf(v, s4, a4); a5 = fmaf(v, s5, a5);
        a6 = fmaf(v, s6, a6); a7 = fmaf(v, s7, a7);
    }

    // store 8 contiguous bf16 (16 B) at agg[w][h*16 + ih*8]
    __hip_bfloat162 o[4];
    o[0].x = __float2bfloat16(a0); o[0].y = __float2bfloat16(a1);
    o[1].x = __float2bfloat16(a2); o[1].y = __float2bfloat16(a3);
    o[2].x = __float2bfloat16(a4); o[2].y = __float2bfloat16(a5);
    o[3].x = __float2bfloat16(a6); o[3].y = __float2bfloat16(a7);
    *(uint4*)(aggb + (size_t)w * 512 + h * 16 + ih * 8) = *(uint4*)o;
}

// ---------------- W -> B-fragment-order bf16 repack -------------------------
// w2frag[((kk*2 + ntile)*64 + lane)*8 + j] = bf16( W[(kk*32 + quad*8 + j)*32 + ntile*16 + (lane&15)] )
__global__ void repack_W_kernel(const float* __restrict__ W,
                                __hip_bfloat16* __restrict__ w2frag) {
    const int tid = blockIdx.x * blockDim.x + threadIdx.x;   // 0..2047
    if (tid >= 2048) return;
    const int lane = tid & 63;
    const int kk   = tid >> 7;
    const int n    = (((tid >> 6) & 1) << 4) + (lane & 15);
    const int kb   = kk * 32 + (lane >> 4) * 8;
#pragma unroll
    for (int j = 0; j < 8; ++j)
        w2frag[tid * 8 + j] = __float2bfloat16(W[(kb + j) * OUTCH + n]);
}

// ---------------- GEMM: out = agg @ W + b via MFMA --------------------------
typedef __attribute__((ext_vector_type(8))) short frag8;
typedef __attribute__((ext_vector_type(4))) float f32x4;

__global__ __launch_bounds__(256)
void gemm_kernel(const __hip_bfloat16* __restrict__ aggb,
                 const __hip_bfloat16* __restrict__ w2frag,
                 const float* __restrict__ b,
                 float* __restrict__ out, int n_atoms) {
    const int wave = (blockIdx.x * blockDim.x + threadIdx.x) >> 6;  // M-tile id
    const int tile0 = wave * 16;
    if (tile0 >= n_atoms) return;
    const int lane = threadIdx.x & 63;
    const int m    = lane & 15;
    const int quad = lane >> 4;

    const int mrow = min(tile0 + m, n_atoms - 1);
    const short* arow = (const short*)aggb + (size_t)mrow * 512 + quad * 8;
    const short* wf   = (const short*)w2frag;

    f32x4 acc0 = {0.f, 0.f, 0.f, 0.f};
    f32x4 acc1 = {0.f, 0.f, 0.f, 0.f};
#pragma unroll
    for (int kk = 0; kk < 16; ++kk) {
        frag8 a  = *(const frag8*)(arow + kk * 32);
        frag8 b0 = *(const frag8*)(wf + ((kk * 2 + 0) * 64 + lane) * 8);
        frag8 b1 = *(const frag8*)(wf + ((kk * 2 + 1) * 64 + lane) * 8);
        acc0 = __builtin_amdgcn_mfma_f32_16x16x32_bf16(a, b0, acc0, 0, 0, 0);
        acc1 = __builtin_amdgcn_mfma_f32_16x16x32_bf16(a, b1, acc1, 0, 0, 0);
    }

    // D: row = quad*4 + reg, col = lane&15
    const float bias0 = b[m];
    const float bias1 = b[16 + m];
    float* obase = out + (size_t)(tile0 + quad * 4) * OUTCH;
#pragma unroll
    for (int r = 0; r < 4; ++r) {
        if (tile0 + quad * 4 + r < n_atoms) {
            obase[r * OUTCH + m]      = acc0[r] + bias0;
            obase[r * OUTCH + 16 + m] = acc1[r] + bias1;
        }
    }
}

// ---------------- launch ---------------------------------------------------
extern "C" void kernel_launch(void* const* d_in, const int* in_sizes, int n_in,
                              void* d_out, int out_size, void* d_ws, size_t ws_size,
                              hipStream_t stream) {
    const float* nf = (const float*)d_in[0];
    const float* ev = (const float*)d_in[1];
    const int*   ei = (const int*)d_in[2];
    const float* W  = (const float*)d_in[3];
    const float* b  = (const float*)d_in[4];
    float* out = (float*)d_out;

    const int n_atoms = in_sizes[0] / HIDDEN;
    const int n_edges = in_sizes[1] / 3;
    const int nblk    = (n_atoms + 255) / 256;

    char* ws = (char*)d_ws;
    size_t off = 0;
    auto carve = [&](size_t bytes) { void* p = ws + off; off = (off + bytes + 255) & ~(size_t)255; return p; };
    __hip_bfloat16* aggb   = (__hip_bfloat16*)carve((size_t)n_atoms * 512 * 2);
    float4*         recs   = (float4*)carve((size_t)n_edges * 16);
    __hip_bfloat16* w2frag = (__hip_bfloat16*)carve(2048 * 8 * 2);
    int* counts    = (int*)carve((size_t)n_atoms * 4);
    int* offsets   = (int*)carve((size_t)n_atoms * 4);
    int* cursor    = (int*)carve((size_t)n_atoms * 4);
    int* partial   = (int*)carve((size_t)n_atoms * 4);
    int* blocksums = (int*)carve((size_t)nblk * 4);

    hipMemsetAsync(counts, 0, (size_t)n_atoms * 4, stream);

    repack_W_kernel<<<8, 256, 0, stream>>>(W, w2frag);
    histogram_kernel<<<(n_edges + 255) / 256, 256, 0, stream>>>(ei, counts, n_edges);
    scan_blocks_kernel<<<nblk, 256, 0, stream>>>(counts, partial, blocksums, n_atoms);
    scan_sums_kernel<<<1, 256, 0, stream>>>(blocksums, nblk);
    add_offsets_kernel<<<nblk, 256, 0, stream>>>(partial, blocksums, offsets, cursor, n_atoms);
    scatter_records_kernel<<<(n_edges + 255) / 256, 256, 0, stream>>>(ev, ei, cursor, recs, n_edges);

    const long long accthreads = (long long)n_atoms * 64;
    accumulate_agg_kernel<<<(int)((accthreads + 255) / 256), 256, 0, stream>>>(
        recs, offsets, counts, nf, aggb, n_atoms);

    const int mtiles = (n_atoms + 15) / 16;
    gemm_kernel<<<(mtiles * 64 + 255) / 256, 256, 0, stream>>>(aggb, w2frag, b, out, n_atoms);
}

// Round 6
// 232.014 us; speedup vs baseline: 1.4375x; 1.1280x over previous
//
#include <hip/hip_runtime.h>
#include <hip/hip_bf16.h>

// Shapes: n_atoms=50000, hidden=32, num_irreps=16, out_ch=32, n_edges=800000
// Pipeline:
//   CSR by target (histogram + scan + scatter). Scatter ALSO evaluates the
//   16 SH basis values per edge and stores them bf16 in CSR position order
//   (32 B/edge), so the hot accumulate loop never recomputes Y.
//   accumulate: one wave per target atom; lane owns (h=lane>>1, ih=lane&1);
//     per edge: uniform src -> nf[src,h] gather (6.4 MB, L2-resident),
//     16 B Y-fragment load, 8 FMAs. agg stored bf16 (1 KB/atom).
//   GEMM: out = agg @ W + b via mfma_f32_16x16x32_bf16 (W pre-swizzled to
//   B-fragment order, 32 KB, cache-resident).

#define HIDDEN 32
#define IRREPS 16
#define OUTCH  32

// ---------------- CSR build -------------------------------------------------
__global__ void histogram_kernel(const int* __restrict__ ei,
                                 int* __restrict__ counts, int n_edges) {
    int e = blockIdx.x * blockDim.x + threadIdx.x;
    if (e < n_edges) atomicAdd(&counts[ei[n_edges + e]], 1);
}

__global__ __launch_bounds__(256)
void scan_blocks_kernel(const int* __restrict__ counts,
                        int* __restrict__ partial,
                        int* __restrict__ blocksums, int n) {
    __shared__ int s[256];
    const int tid = threadIdx.x;
    const int i = blockIdx.x * 256 + tid;
    const int v = (i < n) ? counts[i] : 0;
    s[tid] = v;
    __syncthreads();
    for (int off = 1; off < 256; off <<= 1) {
        int add = 0;
        if (tid >= off) add = s[tid - off];
        __syncthreads();
        if (tid >= off) s[tid] += add;
        __syncthreads();
    }
    if (i < n) partial[i] = s[tid] - v;          // exclusive within block
    if (tid == 255) blocksums[blockIdx.x] = s[255];
}

// nb <= 256: single-block parallel exclusive scan
__global__ __launch_bounds__(256)
void scan_sums_kernel(int* __restrict__ blocksums, int nb) {
    __shared__ int s[256];
    const int tid = threadIdx.x;
    const int v = (tid < nb) ? blocksums[tid] : 0;
    s[tid] = v;
    __syncthreads();
    for (int off = 1; off < 256; off <<= 1) {
        int add = 0;
        if (tid >= off) add = s[tid - off];
        __syncthreads();
        if (tid >= off) s[tid] += add;
        __syncthreads();
    }
    if (tid < nb) blocksums[tid] = s[tid] - v;   // exclusive
}

__global__ void add_offsets_kernel(const int* __restrict__ partial,
                                   const int* __restrict__ blocksums,
                                   int* __restrict__ offsets,
                                   int* __restrict__ cursor, int n) {
    int i = blockIdx.x * blockDim.x + threadIdx.x;
    if (i < n) {
        int off = partial[i] + blocksums[i >> 8];
        offsets[i] = off;
        cursor[i]  = off;
    }
}

// scatter edge -> CSR slot: srcs[pos] = src, Yb[pos][0..15] = SH basis (bf16)
__global__ void scatter_records_kernel(const float* __restrict__ ev,
                                       const int* __restrict__ ei,
                                       int* __restrict__ cursor,
                                       int* __restrict__ srcs,
                                       __hip_bfloat16* __restrict__ Yb,
                                       int n_edges) {
    int e = blockIdx.x * blockDim.x + threadIdx.x;
    if (e >= n_edges) return;
    const int src = ei[e];
    const int tgt = ei[n_edges + e];
    const float vx = ev[3 * e + 0];
    const float vy = ev[3 * e + 1];
    const float vz = ev[3 * e + 2];
    const float r    = sqrtf(vx * vx + vy * vy + vz * vz);
    const float rinv = 1.0f / fmaxf(r, 1e-12f);
    const float x = vx * rinv, y = vy * rinv, z = vz * rinv;
    const float x2 = x * x, y2 = y * y, z2 = z * z;

    float Y[IRREPS];
    Y[0]  = 0.28209479177387814f;
    Y[1]  = 0.4886025119029199f * y;
    Y[2]  = 0.4886025119029199f * z;
    Y[3]  = 0.4886025119029199f * x;
    Y[4]  = 1.0925484305920792f * x * y;
    Y[5]  = 1.0925484305920792f * y * z;
    Y[6]  = 0.31539156525252005f * (3.0f * z2 - 1.0f);
    Y[7]  = 1.0925484305920792f * x * z;
    Y[8]  = 0.5462742152960396f * (x2 - y2);
    Y[9]  = 0.5900435899266435f * y * (3.0f * x2 - y2);
    Y[10] = 2.890611442640554f * x * y * z;
    Y[11] = 0.4570457994644658f * y * (5.0f * z2 - 1.0f);
    Y[12] = 0.3731763325901154f * z * (5.0f * z2 - 3.0f);
    Y[13] = 0.4570457994644658f * x * (5.0f * z2 - 1.0f);
    Y[14] = 1.445305721320277f * z * (x2 - y2);
    Y[15] = 0.5900435899266435f * x * (x2 - 3.0f * y2);

    const int pos = atomicAdd(&cursor[tgt], 1);
    srcs[pos] = src;

    __hip_bfloat162 yp[8];
#pragma unroll
    for (int i = 0; i < 8; ++i) {
        yp[i].x = __float2bfloat16(Y[2 * i]);
        yp[i].y = __float2bfloat16(Y[2 * i + 1]);
    }
    uint4* dst = (uint4*)(Yb + (size_t)pos * IRREPS);
    dst[0] = ((const uint4*)yp)[0];
    dst[1] = ((const uint4*)yp)[1];
}

// ---------------- accumulate: one wave per target atom ---------------------
// lane owns (h = lane>>1, ih = lane&1): cells agg[h][ih*8 .. ih*8+7]
__device__ __forceinline__ float2 bf2f2(unsigned u) {
    return __bfloat1622float2(*(const __hip_bfloat162*)&u);
}

__global__ __launch_bounds__(256)
void accumulate_agg_kernel(const int* __restrict__ srcs,
                           const __hip_bfloat16* __restrict__ Yb,
                           const int* __restrict__ offsets,
                           const int* __restrict__ counts,
                           const float* __restrict__ nf,
                           __hip_bfloat16* __restrict__ aggb, int n_atoms) {
    const int w = (blockIdx.x * blockDim.x + threadIdx.x) >> 6;
    if (w >= n_atoms) return;
    const int lane = threadIdx.x & 63;
    const int h  = lane >> 1;
    const int ih = lane & 1;

    const int start = __builtin_amdgcn_readfirstlane(offsets[w]);
    const int k     = __builtin_amdgcn_readfirstlane(counts[w]);

    const int* sp = srcs + start;
    const __hip_bfloat16* yb = Yb + (size_t)start * IRREPS + ih * 8;

    float a0 = 0.f, a1 = 0.f, a2 = 0.f, a3 = 0.f;
    float a4 = 0.f, a5 = 0.f, a6 = 0.f, a7 = 0.f;

#pragma unroll 2
    for (int j = 0; j < k; ++j) {
        const int src = __builtin_amdgcn_readfirstlane(sp[j]);  // wave-uniform
        const float v = nf[src * HIDDEN + h];    // 128 B/wave, L2-resident
        const uint4 yq = *(const uint4*)(yb + (size_t)j * IRREPS);  // 16 B/lane

        const float2 p0 = bf2f2(yq.x);
        const float2 p1 = bf2f2(yq.y);
        const float2 p2 = bf2f2(yq.z);
        const float2 p3 = bf2f2(yq.w);
        a0 = fmaf(v, p0.x, a0); a1 = fmaf(v, p0.y, a1);
        a2 = fmaf(v, p1.x, a2); a3 = fmaf(v, p1.y, a3);
        a4 = fmaf(v, p2.x, a4); a5 = fmaf(v, p2.y, a5);
        a6 = fmaf(v, p3.x, a6); a7 = fmaf(v, p3.y, a7);
    }

    // store 8 contiguous bf16 (16 B) at agg[w][h*16 + ih*8]
    __hip_bfloat162 o[4];
    o[0].x = __float2bfloat16(a0); o[0].y = __float2bfloat16(a1);
    o[1].x = __float2bfloat16(a2); o[1].y = __float2bfloat16(a3);
    o[2].x = __float2bfloat16(a4); o[2].y = __float2bfloat16(a5);
    o[3].x = __float2bfloat16(a6); o[3].y = __float2bfloat16(a7);
    *(uint4*)(aggb + (size_t)w * 512 + h * 16 + ih * 8) = *(const uint4*)o;
}

// ---------------- W -> B-fragment-order bf16 repack -------------------------
__global__ void repack_W_kernel(const float* __restrict__ W,
                                __hip_bfloat16* __restrict__ w2frag) {
    const int tid = blockIdx.x * blockDim.x + threadIdx.x;   // 0..2047
    if (tid >= 2048) return;
    const int lane = tid & 63;
    const int kk   = tid >> 7;
    const int n    = (((tid >> 6) & 1) << 4) + (lane & 15);
    const int kb   = kk * 32 + (lane >> 4) * 8;
#pragma unroll
    for (int j = 0; j < 8; ++j)
        w2frag[tid * 8 + j] = __float2bfloat16(W[(kb + j) * OUTCH + n]);
}

// ---------------- GEMM: out = agg @ W + b via MFMA --------------------------
typedef __attribute__((ext_vector_type(8))) short frag8;
typedef __attribute__((ext_vector_type(4))) float f32x4;

__global__ __launch_bounds__(256)
void gemm_kernel(const __hip_bfloat16* __restrict__ aggb,
                 const __hip_bfloat16* __restrict__ w2frag,
                 const float* __restrict__ b,
                 float* __restrict__ out, int n_atoms) {
    const int wave = (blockIdx.x * blockDim.x + threadIdx.x) >> 6;  // M-tile id
    const int tile0 = wave * 16;
    if (tile0 >= n_atoms) return;
    const int lane = threadIdx.x & 63;
    const int m    = lane & 15;
    const int quad = lane >> 4;

    const int mrow = min(tile0 + m, n_atoms - 1);
    const short* arow = (const short*)aggb + (size_t)mrow * 512 + quad * 8;
    const short* wf   = (const short*)w2frag;

    f32x4 acc0 = {0.f, 0.f, 0.f, 0.f};
    f32x4 acc1 = {0.f, 0.f, 0.f, 0.f};
#pragma unroll
    for (int kk = 0; kk < 16; ++kk) {
        frag8 a  = *(const frag8*)(arow + kk * 32);
        frag8 b0 = *(const frag8*)(wf + ((kk * 2 + 0) * 64 + lane) * 8);
        frag8 b1 = *(const frag8*)(wf + ((kk * 2 + 1) * 64 + lane) * 8);
        acc0 = __builtin_amdgcn_mfma_f32_16x16x32_bf16(a, b0, acc0, 0, 0, 0);
        acc1 = __builtin_amdgcn_mfma_f32_16x16x32_bf16(a, b1, acc1, 0, 0, 0);
    }

    // D: row = quad*4 + reg, col = lane&15
    const float bias0 = b[m];
    const float bias1 = b[16 + m];
    float* obase = out + (size_t)(tile0 + quad * 4) * OUTCH;
#pragma unroll
    for (int r = 0; r < 4; ++r) {
        if (tile0 + quad * 4 + r < n_atoms) {
            obase[r * OUTCH + m]      = acc0[r] + bias0;
            obase[r * OUTCH + 16 + m] = acc1[r] + bias1;
        }
    }
}

// ---------------- launch ---------------------------------------------------
extern "C" void kernel_launch(void* const* d_in, const int* in_sizes, int n_in,
                              void* d_out, int out_size, void* d_ws, size_t ws_size,
                              hipStream_t stream) {
    const float* nf = (const float*)d_in[0];
    const float* ev = (const float*)d_in[1];
    const int*   ei = (const int*)d_in[2];
    const float* W  = (const float*)d_in[3];
    const float* b  = (const float*)d_in[4];
    float* out = (float*)d_out;

    const int n_atoms = in_sizes[0] / HIDDEN;
    const int n_edges = in_sizes[1] / 3;
    const int nblk    = (n_atoms + 255) / 256;

    char* ws = (char*)d_ws;
    size_t off = 0;
    auto carve = [&](size_t bytes) { void* p = ws + off; off = (off + bytes + 255) & ~(size_t)255; return p; };
    __hip_bfloat16* aggb   = (__hip_bfloat16*)carve((size_t)n_atoms * 512 * 2);   // 51.2 MB
    __hip_bfloat16* Yb     = (__hip_bfloat16*)carve((size_t)n_edges * IRREPS * 2); // 25.6 MB
    int*            srcs   = (int*)carve((size_t)n_edges * 4);                    // 3.2 MB
    __hip_bfloat16* w2frag = (__hip_bfloat16*)carve(2048 * 8 * 2);
    int* counts    = (int*)carve((size_t)n_atoms * 4);
    int* offsets   = (int*)carve((size_t)n_atoms * 4);
    int* cursor    = (int*)carve((size_t)n_atoms * 4);
    int* partial   = (int*)carve((size_t)n_atoms * 4);
    int* blocksums = (int*)carve((size_t)nblk * 4);

    hipMemsetAsync(counts, 0, (size_t)n_atoms * 4, stream);

    repack_W_kernel<<<8, 256, 0, stream>>>(W, w2frag);
    histogram_kernel<<<(n_edges + 255) / 256, 256, 0, stream>>>(ei, counts, n_edges);
    scan_blocks_kernel<<<nblk, 256, 0, stream>>>(counts, partial, blocksums, n_atoms);
    scan_sums_kernel<<<1, 256, 0, stream>>>(blocksums, nblk);
    add_offsets_kernel<<<nblk, 256, 0, stream>>>(partial, blocksums, offsets, cursor, n_atoms);
    scatter_records_kernel<<<(n_edges + 255) / 256, 256, 0, stream>>>(
        ev, ei, cursor, srcs, Yb, n_edges);

    const long long accthreads = (long long)n_atoms * 64;
    accumulate_agg_kernel<<<(int)((accthreads + 255) / 256), 256, 0, stream>>>(
        srcs, Yb, offsets, counts, nf, aggb, n_atoms);

    const int mtiles = (n_atoms + 15) / 16;
    gemm_kernel<<<(mtiles * 64 + 255) / 256, 256, 0, stream>>>(aggb, w2frag, b, out, n_atoms);
}